// Round 3
// baseline (271.587 us; speedup 1.0000x reference)
//
#include <hip/hip_runtime.h>
#include <math.h>

// Problem: B=8, C=64, T=16, H=64, W=64, text_dim=768
// out[b,c,:,h,w] = D^T diag(w[b,c,:]) D @ r[b,c,:,h,w]
// w[b, c*16+k] = sigmoid(E_txt[b] . Wf[c*16+k] + bf[c*16+k])
// M_bc = D^T diag(w) D is SYMMETRIC -> row k == column k (exploited in mod).

#define HW4 1024         // H*W/4 (float4 units)

// ---------------- Kernel A: gate GEMM + sigmoid -> w[8192] ----------------
__global__ __launch_bounds__(256) void gate_kernel(
    const float* __restrict__ E,    // (8, 768)
    const float* __restrict__ Wf,   // (1024, 768)
    const float* __restrict__ bf,   // (1024,)
    float* __restrict__ wout)       // (8192,) indexed [bc*16+k]
{
    const int wave = threadIdx.x >> 6;
    const int lane = threadIdx.x & 63;
    const int ct   = blockIdx.x * 4 + wave;

    const float4* W4 = (const float4*)(Wf) + ct * 192;
    const float4* E4 = (const float4*)E;

    float acc[8];
#pragma unroll
    for (int b = 0; b < 8; ++b) acc[b] = 0.f;

#pragma unroll
    for (int j = 0; j < 3; ++j) {
        float4 a = W4[j * 64 + lane];
#pragma unroll
        for (int b = 0; b < 8; ++b) {
            float4 e = E4[b * 192 + j * 64 + lane];
            acc[b] = fmaf(a.x, e.x, acc[b]);
            acc[b] = fmaf(a.y, e.y, acc[b]);
            acc[b] = fmaf(a.z, e.z, acc[b]);
            acc[b] = fmaf(a.w, e.w, acc[b]);
        }
    }
#pragma unroll
    for (int off = 32; off >= 1; off >>= 1) {
#pragma unroll
        for (int b = 0; b < 8; ++b)
            acc[b] += __shfl_xor(acc[b], off, 64);
    }
    const float bias = bf[ct];
#pragma unroll
    for (int b = 0; b < 8; ++b) {
        if (lane == b) {
            float s = acc[b] + bias;
            wout[b * 1024 + ct] = 1.0f / (1.0f + expf(-s));
        }
    }
}

// ---------------- Kernel B: M[bc][i][j] = sum_k D[k][i] w[k] D[k][j] ----------------
__global__ __launch_bounds__(256) void buildM_kernel(
    const float* __restrict__ wbuf,  // (8192,) [bc*16+k]
    float* __restrict__ Mout)        // (512, 256)
{
    __shared__ float Dl[16][16];
    __shared__ float wv[16];
    const int tid = threadIdx.x;
    const int bc  = blockIdx.x;
    {
        int k = tid >> 4, n = tid & 15;
        float v = (k == 0) ? 0.25f
                           : cospif((n + 0.5f) * (float)k * (1.0f / 16.0f)) * 0.35355339059327373f;
        Dl[k][n] = v;
        if (tid < 16) wv[tid] = wbuf[bc * 16 + tid];
    }
    __syncthreads();
    int i = tid >> 4, j = tid & 15;
    float s = 0.f;
#pragma unroll
    for (int k = 0; k < 16; ++k)
        s = fmaf(Dl[k][i] * wv[k], Dl[k][j], s);
    Mout[bc * 256 + tid] = s;   // coalesced; M is symmetric
}

// ---------------- Kernel C: y = M @ x streaming transform ----------------
// 2048 blocks x 256 threads (4 independent waves). bc = blk>>2.
// wave w handles hw-chunk (blk&3)*4 + w (64 float4 per chunk).
// k-major accumulation (compute starts at vmcnt(15)); t-loop split in two
// halves of 8 so y shrinks to 8 float4 -> <=128 VGPRs -> 4 waves/SIMD.
// M symmetric: column k read as row k via two ds_read_b128.
__global__ __launch_bounds__(256, 4) void mod_kernel(
    const float* __restrict__ r,     // (512, 16, 4096)
    const float* __restrict__ M,     // (512, 256)
    float* __restrict__ out)
{
    __shared__ __align__(16) float Ms[256];
    const int tid  = threadIdx.x;
    const int wave = tid >> 6;
    const int lane = tid & 63;
    const int bc   = blockIdx.x >> 2;

    Ms[tid] = M[bc * 256 + tid];     // one coalesced 1 KB load
    __syncthreads();

    const size_t base = (size_t)bc * (16 * 4096);
    const float4* rp = (const float4*)(r + base);
    float4*       op = (float4*)(out + base);
    const int col = ((blockIdx.x & 3) * 4 + wave) * 64 + lane;

    float4 x[16];
#pragma unroll
    for (int k = 0; k < 16; ++k)
        x[k] = rp[k * HW4 + col];

    // ---- t = 0..7 ----
    {
        float4 y[8];
#pragma unroll
        for (int t = 0; t < 8; ++t) y[t] = make_float4(0.f, 0.f, 0.f, 0.f);
#pragma unroll
        for (int k = 0; k < 16; ++k) {
            const float4 m0 = *(const float4*)&Ms[k * 16 + 0];
            const float4 m1 = *(const float4*)&Ms[k * 16 + 4];
            const float4 xk = x[k];
            const float mv[8] = {m0.x, m0.y, m0.z, m0.w, m1.x, m1.y, m1.z, m1.w};
#pragma unroll
            for (int t = 0; t < 8; ++t) {
                y[t].x = fmaf(mv[t], xk.x, y[t].x);
                y[t].y = fmaf(mv[t], xk.y, y[t].y);
                y[t].z = fmaf(mv[t], xk.z, y[t].z);
                y[t].w = fmaf(mv[t], xk.w, y[t].w);
            }
        }
#pragma unroll
        for (int t = 0; t < 8; ++t)
            op[t * HW4 + col] = y[t];
    }

    // ---- t = 8..15 ----
    {
        float4 y[8];
#pragma unroll
        for (int t = 0; t < 8; ++t) y[t] = make_float4(0.f, 0.f, 0.f, 0.f);
#pragma unroll
        for (int k = 0; k < 16; ++k) {
            const float4 m0 = *(const float4*)&Ms[k * 16 + 8];
            const float4 m1 = *(const float4*)&Ms[k * 16 + 12];
            const float4 xk = x[k];
            const float mv[8] = {m0.x, m0.y, m0.z, m0.w, m1.x, m1.y, m1.z, m1.w};
#pragma unroll
            for (int t = 0; t < 8; ++t) {
                y[t].x = fmaf(mv[t], xk.x, y[t].x);
                y[t].y = fmaf(mv[t], xk.y, y[t].y);
                y[t].z = fmaf(mv[t], xk.z, y[t].z);
                y[t].w = fmaf(mv[t], xk.w, y[t].w);
            }
        }
#pragma unroll
        for (int t = 0; t < 8; ++t)
            op[(t + 8) * HW4 + col] = y[t];
    }
}

extern "C" void kernel_launch(void* const* d_in, const int* in_sizes, int n_in,
                              void* d_out, int out_size, void* d_ws, size_t ws_size,
                              hipStream_t stream) {
    const float* r  = (const float*)d_in[0];   // 33554432
    const float* E  = (const float*)d_in[1];   // 6144
    const float* Wf = (const float*)d_in[2];   // 786432
    const float* bf = (const float*)d_in[3];   // 1024
    float* out = (float*)d_out;
    float* w   = (float*)d_ws;                  // 8192 floats
    float* M   = (float*)d_ws + 8192;           // 512*256 floats

    gate_kernel  <<<256, 256, 0, stream>>>(E, Wf, bf, w);
    buildM_kernel<<<512, 256, 0, stream>>>(w, M);
    mod_kernel   <<<2048, 256, 0, stream>>>(r, M, out);
}